// Round 8
// baseline (84.122 us; speedup 1.0000x reference)
//
#include <hip/hip_runtime.h>
#include <math.h>

// Problem constants
#define Bb 4
#define Cc 64
#define Hh 64
#define Ww 64
#define Ss 20

constexpr int XC = Hh * Ww * Ss;   // 81920  : x channel stride (floats)
constexpr int XH = Ww * Ss;        // 1280   : x row stride
constexpr int XW = Ss;             // 20     : x col stride
constexpr int XB = Cc * XC;        // 5242880: x batch stride

// ws layout (floats): [0,576) Weff[tap][c'], [576,585) btap[tap]

// ---------------------------------------------------------------------------
// Kernel 1: fold the K-branch 1x1 conv into the 3x3 conv.
// Weff[tap][c'] = sum_c w2[0,64+c,tap] * w1[64+c, c']
// btap[tap]     = sum_c w2[0,64+c,tap] * b1[64+c]
// ---------------------------------------------------------------------------
__global__ void ct_fold_weights(const float* __restrict__ w1,
                                const float* __restrict__ b1,
                                const float* __restrict__ w2,
                                float* __restrict__ ws) {
    int tid = threadIdx.x;
    if (tid < 576) {
        int tap = tid >> 6, cp = tid & 63;
        float acc = 0.f;
        #pragma unroll 8
        for (int c = 0; c < 64; ++c)
            acc += w2[(64 + c) * 9 + tap] * w1[(64 + c) * 64 + cp];
        ws[tid] = acc;
    } else if (tid < 585) {
        int tap = tid - 576;
        float acc = 0.f;
        for (int c = 0; c < 64; ++c)
            acc += w2[(64 + c) * 9 + tap] * b1[64 + c];
        ws[576 + tap] = acc;
    }
}

// ---------------------------------------------------------------------------
// Fused kernel: conv(Bk) + softmax + xbar + 1x1(R) + broadcast store.
// Block = (b, h, wq): 16 sites (w = wq*16 + w16). 320 threads, grid 1024.
// Phase 1 (tid = cg*80 + w16*5 + t4): gather conv, cg owns 16 channels;
//   144 x 16B clamped+masked loads per thread (proven R3 pattern);
//   partial Bk[cg][w16][t] into LDS.
// Phase 2 (tid = sw*20 + t): reduce 4 partials + valid-tap bias; then 16
//   threads do the 20-wide softmax serially (proven attn_out pattern).
// Phase 3/4 (tid = cq*16 + si, cq<16): xbar over center row (L2-hot from
//   phase 1), R via LDS-transposed w1v, broadcast store along s.
// x is read from HBM exactly once; no Bk round-trip; one launch.
// ---------------------------------------------------------------------------
__global__ __launch_bounds__(320, 5) void ct_fused(
        const float* __restrict__ x,
        const float* __restrict__ w1,
        const float* __restrict__ b1,
        const float* __restrict__ ws,
        float* __restrict__ out) {
    __shared__ float weff[576];
    __shared__ float btL[9];
    __shared__ float w1t[64 * 65];   // w1t[cp*65 + c] = w1v[c][cp]
    __shared__ float bkp[4][16][20];
    __shared__ float psm[16][20];
    __shared__ float xsh[16][65];
    int tid = threadIdx.x;

    for (int i = tid; i < 576; i += 320) weff[i] = ws[i];
    if (tid < 9) btL[tid] = ws[576 + tid];
    #pragma unroll
    for (int k = 0; k < 13; ++k) {        // 13*320 >= 4096
        int j = tid + k * 320;
        if (j < 4096) {
            int r = j >> 6, q = j & 63;
            w1t[q * 65 + r] = w1[8192 + j];   // w1v row r, col q
        }
    }

    // XCD swizzle: XCD owns contiguous (b,h) range -> h-halo L2 reuse.
    int g = (blockIdx.x & 7) * 128 + (blockIdx.x >> 3);
    int wq = g & 3;
    int h  = (g >> 2) & 63;
    int b  = g >> 8;

    // ---- phase 1: partial conv ----
    int w16 = (tid / 5) & 15, t4 = tid % 5, cg = tid / 80;  // cg in [0,4)
    int w = wq * 16 + w16;

    float vmask[9];
    int off[9];
    #pragma unroll
    for (int dh = 0; dh < 3; ++dh) {
        int hh = h + dh - 1;
        float hv = (hh >= 0 && hh < Hh) ? 1.f : 0.f;
        int hcl = hh < 0 ? 0 : (hh > Hh - 1 ? Hh - 1 : hh);
        #pragma unroll
        for (int dw = 0; dw < 3; ++dw) {
            int wc = w + dw - 1;
            float wvd = (wc >= 0 && wc < Ww) ? 1.f : 0.f;
            int wcl = wc < 0 ? 0 : (wc > Ww - 1 ? Ww - 1 : wc);
            vmask[dh * 3 + dw] = hv * wvd;
            off[dh * 3 + dw] = hcl * XH + wcl * XW;
        }
    }
    __syncthreads();   // weff ready

    float4 acc = make_float4(0.f, 0.f, 0.f, 0.f);
    const float* xb = x + b * XB + cg * 16 * XC + t4 * 4;
    #pragma unroll 2
    for (int i = 0; i < 16; ++i) {
        const float* xc = xb + i * XC;
        #pragma unroll
        for (int tap = 0; tap < 9; ++tap) {
            float wv = weff[tap * 64 + cg * 16 + i] * vmask[tap];
            const float4 xv = *reinterpret_cast<const float4*>(xc + off[tap]);
            acc.x = fmaf(wv, xv.x, acc.x);
            acc.y = fmaf(wv, xv.y, acc.y);
            acc.z = fmaf(wv, xv.z, acc.z);
            acc.w = fmaf(wv, xv.w, acc.w);
        }
    }
    *reinterpret_cast<float4*>(&bkp[cg][w16][t4 * 4]) = acc;
    __syncthreads();

    // ---- phase 2: reduce + bias, then softmax ----
    {
        int sw = tid / 20, t = tid % 20;      // exactly 320 threads
        float v = bkp[0][sw][t] + bkp[1][sw][t] + bkp[2][sw][t] + bkp[3][sw][t];
        int wsite = wq * 16 + sw;
        float bs = 0.f;
        #pragma unroll
        for (int dh = 0; dh < 3; ++dh) {
            int hh = h + dh - 1;
            if (hh < 0 || hh >= Hh) continue;
            #pragma unroll
            for (int dw = 0; dw < 3; ++dw) {
                int wc = wsite + dw - 1;
                if (wc < 0 || wc >= Ww) continue;
                bs += btL[dh * 3 + dw];
            }
        }
        psm[sw][t] = v + bs;
    }
    __syncthreads();

    if (tid < 16) {
        float p[20];
        #pragma unroll
        for (int i = 0; i < 20; ++i) p[i] = psm[tid][i];
        float m = p[0];
        #pragma unroll
        for (int i = 1; i < 20; ++i) m = fmaxf(m, p[i]);
        float ssum = 0.f;
        #pragma unroll
        for (int i = 0; i < 20; ++i) { p[i] = __expf(p[i] - m); ssum += p[i]; }
        float inv = 1.f / ssum;
        #pragma unroll
        for (int i = 0; i < 20; ++i) psm[tid][i] = p[i] * inv;
    }
    __syncthreads();

    // ---- phase 3: xbar (center row, L2-hot) ----
    int si = tid & 15, cq = tid >> 4;        // cq in [0,20); only cq<16 work
    int wsite = wq * 16 + si;
    if (cq < 16) {
        #pragma unroll
        for (int k = 0; k < 4; ++k) {
            int c = cq * 4 + k;
            const float* xp = x + (b * 64 + c) * XC + h * XH + wsite * 20;
            float xbv = 0.f;
            #pragma unroll
            for (int i = 0; i < 5; ++i) {
                float4 xv = reinterpret_cast<const float4*>(xp)[i];
                xbv = fmaf(psm[si][4 * i],     xv.x, xbv);
                xbv = fmaf(psm[si][4 * i + 1], xv.y, xbv);
                xbv = fmaf(psm[si][4 * i + 2], xv.z, xbv);
                xbv = fmaf(psm[si][4 * i + 3], xv.w, xbv);
            }
            xsh[si][c] = xbv;
        }
    }
    __syncthreads();

    // ---- phase 4: R = b1v + w1v * xbar ; broadcast along s ----
    if (cq < 16) {
        #pragma unroll
        for (int k = 0; k < 4; ++k) {
            int c = cq * 4 + k;
            float R = b1[128 + c];
            #pragma unroll 8
            for (int cp = 0; cp < 64; ++cp)
                R = fmaf(w1t[cp * 65 + c], xsh[si][cp], R);
            float* op = out + (b * 64 + c) * XC + h * XH + wsite * 20;
            float4 rv = make_float4(R, R, R, R);
            #pragma unroll
            for (int s4 = 0; s4 < 5; ++s4)
                reinterpret_cast<float4*>(op)[s4] = rv;
        }
    }
}

extern "C" void kernel_launch(void* const* d_in, const int* in_sizes, int n_in,
                              void* d_out, int out_size, void* d_ws, size_t ws_size,
                              hipStream_t stream) {
    const float* x  = (const float*)d_in[0];
    const float* w1 = (const float*)d_in[1];
    const float* b1 = (const float*)d_in[2];
    const float* w2 = (const float*)d_in[3];
    // d_in[4] (b2) is mathematically dead: it cancels in the softmax over t.
    float* ws  = (float*)d_ws;
    float* out = (float*)d_out;

    ct_fold_weights<<<1, 640, 0, stream>>>(w1, b1, w2, ws);
    ct_fused<<<1024, 320, 0, stream>>>(x, w1, b1, ws, out);
}

// Round 9
// 81.970 us; speedup vs baseline: 1.0263x; 1.0263x over previous
//
#include <hip/hip_runtime.h>
#include <math.h>

// Problem constants
#define Bb 4
#define Cc 64
#define Hh 64
#define Ww 64
#define Ss 20

constexpr int XC = Hh * Ww * Ss;   // 81920  : x channel stride (floats)
constexpr int XH = Ww * Ss;        // 1280   : x row stride
constexpr int XW = Ss;             // 20     : x col stride
constexpr int XB = Cc * XC;        // 5242880: x batch stride
constexpr int NSITE = Bb * Hh * Ww;    // 16384
constexpr int BKPLANE = NSITE * Ss;    // 327680 floats per partial plane

// ws layout (floats): [0,576) Weff[tap][c'], [576,585) btap[tap],
//                     [640, 640 + NPART*BKPLANE) partial Bk planes

// ---------------------------------------------------------------------------
// Kernel 1: fold the K-branch 1x1 conv into the 3x3 conv.
// ---------------------------------------------------------------------------
__global__ void ct_fold_weights(const float* __restrict__ w1,
                                const float* __restrict__ b1,
                                const float* __restrict__ w2,
                                float* __restrict__ ws) {
    int tid = threadIdx.x;
    if (tid < 576) {
        int tap = tid >> 6, cp = tid & 63;
        float acc = 0.f;
        #pragma unroll 8
        for (int c = 0; c < 64; ++c)
            acc += w2[(64 + c) * 9 + tap] * w1[(64 + c) * 64 + cp];
        ws[tid] = acc;
    } else if (tid < 585) {
        int tap = tid - 576;
        float acc = 0.f;
        for (int c = 0; c < 64; ++c)
            acc += w2[(64 + c) * 9 + tap] * b1[64 + c];
        ws[576 + tap] = acc;
    }
}

// ---------------------------------------------------------------------------
// Kernel 2 (h-paired gather): partial Bk over a channel slice, 2 output rows
// per thread. Proven conv_bk stream shape (c-loop, clamped addresses, mask
// folded into weights, unroll 2, no barriers/stores inside the loop), but
// the 4 input rows (h0-1..h0+2) are loaded ONCE and feed both outputs:
// 12 loads + 72 FMA per channel -> 96 loads/thread for 2 outputs (vs 144
// for 1 output in conv_bk<4>). Logical L2 traffic drops 33%.
// NCP=8, grid = 8 parts * 4 b * 32 hpairs = 1024 (conv4's proven occupancy).
// ---------------------------------------------------------------------------
template<int NCP>
__global__ __launch_bounds__(320) void ct_conv_hpair(
        const float* __restrict__ x,
        const float* __restrict__ ws,
        float* __restrict__ bk) {
    constexpr int NPART = 64 / NCP;
    constexpr int NBLK = NPART * 4 * 32;
    __shared__ float wsl[9 * NCP];
    __shared__ float btL[9];
    int tid = threadIdx.x;

    // XCD swizzle: consecutive g on one XCD = consecutive h-pairs (halo reuse)
    int g = (blockIdx.x & 7) * (NBLK / 8) + (blockIdx.x >> 3);
    int hp = g & 31;
    int b = (g >> 5) & 3;
    int part = g >> 7;

    if (tid < 9 * NCP)
        wsl[tid] = ws[(tid / NCP) * 64 + part * NCP + (tid % NCP)];
    if (tid < 9) btL[tid] = ws[576 + tid];
    __syncthreads();

    int w = tid / 5, t4 = tid % 5;
    int h0 = hp * 2;

    // w-shift masks and clamped column offsets
    float sm[3];
    sm[0] = (w == 0) ? 0.f : 1.f;
    sm[1] = 1.f;
    sm[2] = (w == 63) ? 0.f : 1.f;
    int cw[3];
    cw[0] = ((w == 0) ? 0 : w - 1) * XW;
    cw[1] = w * XW;
    cw[2] = ((w == 63) ? 63 : w + 1) * XW;

    // 4 input rows: validity mask + clamped row offset
    float hv[4];
    int ro[4];
    #pragma unroll
    for (int rr = 0; rr < 4; ++rr) {
        int hr = h0 - 1 + rr;
        hv[rr] = (hr >= 0 && hr < Hh) ? 1.f : 0.f;
        int hcl = hr < 0 ? 0 : (hr > Hh - 1 ? Hh - 1 : hr);
        ro[rr] = hcl * XH;
    }

    // per-output-tap masks: out0 (row h0) uses input rows rr=r;
    // out1 (row h0+1) uses rows rr=r+1.
    float vm0[9], vm1[9];
    #pragma unroll
    for (int r = 0; r < 3; ++r)
        #pragma unroll
        for (int s = 0; s < 3; ++s) {
            vm0[r * 3 + s] = hv[r]     * sm[s];
            vm1[r * 3 + s] = hv[r + 1] * sm[s];
        }

    float bs0 = 0.f, bs1 = 0.f;
    if (part == 0) {
        #pragma unroll
        for (int t = 0; t < 9; ++t) { bs0 += btL[t] * vm0[t]; bs1 += btL[t] * vm1[t]; }
    }
    float4 acc0 = make_float4(bs0, bs0, bs0, bs0);
    float4 acc1 = make_float4(bs1, bs1, bs1, bs1);

    const float* xb = x + b * XB + part * NCP * XC + t4 * 4;
    #pragma unroll 2
    for (int c = 0; c < NCP; ++c) {
        const float* xc = xb + c * XC;
        float4 v[4][3];
        #pragma unroll
        for (int rr = 0; rr < 4; ++rr)
            #pragma unroll
            for (int s = 0; s < 3; ++s)
                v[rr][s] = *reinterpret_cast<const float4*>(xc + ro[rr] + cw[s]);

        #pragma unroll
        for (int r = 0; r < 3; ++r) {
            #pragma unroll
            for (int s = 0; s < 3; ++s) {
                float wgt = wsl[(r * 3 + s) * NCP + c];
                float w0 = wgt * vm0[r * 3 + s];
                float w1v = wgt * vm1[r * 3 + s];
                float4 va = v[r][s];
                float4 vb = v[r + 1][s];
                acc0.x = fmaf(w0, va.x, acc0.x);
                acc0.y = fmaf(w0, va.y, acc0.y);
                acc0.z = fmaf(w0, va.z, acc0.z);
                acc0.w = fmaf(w0, va.w, acc0.w);
                acc1.x = fmaf(w1v, vb.x, acc1.x);
                acc1.y = fmaf(w1v, vb.y, acc1.y);
                acc1.z = fmaf(w1v, vb.z, acc1.z);
                acc1.w = fmaf(w1v, vb.w, acc1.w);
            }
        }
    }

    float* bkp = bk + part * BKPLANE;
    int site0 = (b * 64 + h0) * 64 + w;
    *reinterpret_cast<float4*>(bkp + site0 * 20 + t4 * 4) = acc0;
    *reinterpret_cast<float4*>(bkp + (site0 + 64) * 20 + t4 * 4) = acc1;
}

// ---------------------------------------------------------------------------
// Kernel 2 fallback (gather, 1 row/thread) — proven R3 kernel.
// ---------------------------------------------------------------------------
template<int NPART>
__global__ __launch_bounds__(320) void ct_conv_bk(
        const float* __restrict__ x,
        const float* __restrict__ ws,
        float* __restrict__ bk) {
    __shared__ float weff[576];
    __shared__ float btap[9];
    int tid = threadIdx.x;
    for (int i = tid; i < 576; i += 320) weff[i] = ws[i];
    if (tid < 9) btap[tid] = ws[576 + tid];
    __syncthreads();

    constexpr int NCP = 64 / NPART;
    constexpr int CHUNK = 256 * NPART / 8;
    int g = (blockIdx.x & 7) * CHUNK + (blockIdx.x >> 3);
    int part = g >> 8;
    int nl = g & 255;
    int b = nl >> 6, h = nl & 63;
    int w = tid / 5, t4 = tid % 5;

    float vmask[9];
    int off[9];
    #pragma unroll
    for (int dh = 0; dh < 3; ++dh) {
        int hh = h + dh - 1;
        float hvv = (hh >= 0 && hh < Hh) ? 1.f : 0.f;
        int hcl = hh < 0 ? 0 : (hh > Hh - 1 ? Hh - 1 : hh);
        #pragma unroll
        for (int dw = 0; dw < 3; ++dw) {
            int wc = w + dw - 1;
            float wvd = (wc >= 0 && wc < Ww) ? 1.f : 0.f;
            int wcl = wc < 0 ? 0 : (wc > Ww - 1 ? Ww - 1 : wc);
            vmask[dh * 3 + dw] = hvv * wvd;
            off[dh * 3 + dw] = hcl * XH + wcl * XW;
        }
    }

    float bsum = 0.f;
    if (part == 0) {
        #pragma unroll
        for (int tap = 0; tap < 9; ++tap) bsum += btap[tap] * vmask[tap];
    }
    float4 acc = make_float4(bsum, bsum, bsum, bsum);

    const float* xb = x + b * XB + part * NCP * XC + t4 * 4;
    #pragma unroll 2
    for (int c = 0; c < NCP; ++c) {
        const float* xc = xb + c * XC;
        #pragma unroll
        for (int tap = 0; tap < 9; ++tap) {
            float wv = weff[tap * 64 + part * NCP + c] * vmask[tap];
            const float4 xv = *reinterpret_cast<const float4*>(xc + off[tap]);
            acc.x = fmaf(wv, xv.x, acc.x);
            acc.y = fmaf(wv, xv.y, acc.y);
            acc.z = fmaf(wv, xv.z, acc.z);
            acc.w = fmaf(wv, xv.w, acc.w);
        }
    }
    int site = nl * 64 + w;
    *reinterpret_cast<float4*>(bk + part * BKPLANE + site * 20 + t4 * 4) = acc;
}

// ---------------------------------------------------------------------------
// Kernel 3 (proven R4): block = 8 consecutive sites, 256 threads, grid 2048.
// ---------------------------------------------------------------------------
template<int NPART>
__global__ __launch_bounds__(256) void ct_attn_out(
        const float* __restrict__ x,
        const float* __restrict__ w1,
        const float* __restrict__ b1,
        const float* __restrict__ bk,
        float* __restrict__ out) {
    __shared__ float w1t[64 * 65];   // w1t[cp*65 + c] = w1v[c][cp]
    __shared__ float psm[8][20];
    __shared__ float xsh[8][65];
    int tid = threadIdx.x;
    #pragma unroll
    for (int k = 0; k < 16; ++k) {
        int j = tid + k * 256;
        int r = j >> 6, q = j & 63;
        w1t[q * 65 + r] = w1[8192 + j];
    }

    int site0 = blockIdx.x * 8;

    if (tid < 160) {
        int si = tid / 20, i = tid % 20;
        float v = 0.f;
        #pragma unroll
        for (int pt = 0; pt < NPART; ++pt)
            v += bk[pt * BKPLANE + (site0 + si) * 20 + i];
        psm[si][i] = v;
    }
    __syncthreads();

    if (tid < 8) {
        float p[20];
        #pragma unroll
        for (int i = 0; i < 20; ++i) p[i] = psm[tid][i];
        float m = p[0];
        #pragma unroll
        for (int i = 1; i < 20; ++i) m = fmaxf(m, p[i]);
        float ssum = 0.f;
        #pragma unroll
        for (int i = 0; i < 20; ++i) { p[i] = __expf(p[i] - m); ssum += p[i]; }
        float inv = 1.f / ssum;
        #pragma unroll
        for (int i = 0; i < 20; ++i) psm[tid][i] = p[i] * inv;
    }
    __syncthreads();

    int si = tid & 7, cg = tid >> 3;
    int site = site0 + si;
    int b = site >> 12, hw = site & 4095;

    #pragma unroll
    for (int k = 0; k < 2; ++k) {
        int c = cg * 2 + k;
        const float* xp = x + (b * 64 + c) * XC + hw * 20;
        float xbv = 0.f;
        #pragma unroll
        for (int i = 0; i < 5; ++i) {
            float4 xv = reinterpret_cast<const float4*>(xp)[i];
            xbv = fmaf(psm[si][4 * i],     xv.x, xbv);
            xbv = fmaf(psm[si][4 * i + 1], xv.y, xbv);
            xbv = fmaf(psm[si][4 * i + 2], xv.z, xbv);
            xbv = fmaf(psm[si][4 * i + 3], xv.w, xbv);
        }
        xsh[si][c] = xbv;
    }
    __syncthreads();

    #pragma unroll
    for (int k = 0; k < 2; ++k) {
        int c = cg * 2 + k;
        float R = b1[128 + c];
        #pragma unroll 8
        for (int cp = 0; cp < 64; ++cp)
            R = fmaf(w1t[cp * 65 + c], xsh[si][cp], R);
        float* op = out + (b * 64 + c) * XC + hw * 20;
        float4 rv = make_float4(R, R, R, R);
        #pragma unroll
        for (int s4 = 0; s4 < 5; ++s4)
            reinterpret_cast<float4*>(op)[s4] = rv;
    }
}

extern "C" void kernel_launch(void* const* d_in, const int* in_sizes, int n_in,
                              void* d_out, int out_size, void* d_ws, size_t ws_size,
                              hipStream_t stream) {
    const float* x  = (const float*)d_in[0];
    const float* w1 = (const float*)d_in[1];
    const float* b1 = (const float*)d_in[2];
    const float* w2 = (const float*)d_in[3];
    // d_in[4] (b2) is mathematically dead: it cancels in the softmax over t.
    float* ws    = (float*)d_ws;
    float* bkbuf = ws + 640;
    float* out   = (float*)d_out;

    ct_fold_weights<<<1, 640, 0, stream>>>(w1, b1, w2, ws);

    size_t need8 = (size_t)(640 + 8 * BKPLANE) * sizeof(float);
    size_t need4 = (size_t)(640 + 4 * BKPLANE) * sizeof(float);
    if (ws_size >= need8) {
        // NCP=8 -> NPART=8, grid = 8*4*32 = 1024 h-paired blocks
        ct_conv_hpair<8><<<1024, 320, 0, stream>>>(x, ws, bkbuf);
        ct_attn_out<8><<<2048, 256, 0, stream>>>(x, w1, b1, bkbuf, out);
    } else if (ws_size >= need4) {
        ct_conv_bk<4><<<1024, 320, 0, stream>>>(x, ws, bkbuf);
        ct_attn_out<4><<<2048, 256, 0, stream>>>(x, w1, b1, bkbuf, out);
    } else {
        ct_conv_bk<1><<<256, 320, 0, stream>>>(x, ws, bkbuf);
        ct_attn_out<1><<<2048, 256, 0, stream>>>(x, w1, b1, bkbuf, out);
    }
}

// Round 10
// 74.694 us; speedup vs baseline: 1.1262x; 1.0974x over previous
//
#include <hip/hip_runtime.h>
#include <math.h>

// Problem constants
#define Bb 4
#define Cc 64
#define Hh 64
#define Ww 64
#define Ss 20

constexpr int XC = Hh * Ww * Ss;   // 81920  : x channel stride (floats)
constexpr int XH = Ww * Ss;        // 1280   : x row stride
constexpr int XW = Ss;             // 20     : x col stride
constexpr int XB = Cc * XC;        // 5242880: x batch stride
constexpr int NSITE = Bb * Hh * Ww;    // 16384
constexpr int BKPLANE = NSITE * Ss;    // 327680 floats per partial plane

// ws layout (floats): [0,576) Weff[tap][c'], [576,585) btap[tap],
//                     [640, 640 + NPART*BKPLANE) partial Bk planes

// ---------------------------------------------------------------------------
// Kernel 1: fold the K-branch 1x1 conv into the 3x3 conv.
// Weff[tap][c'] = sum_c w2[0,64+c,tap] * w1[64+c, c']
// btap[tap]     = sum_c w2[0,64+c,tap] * b1[64+c]
// ---------------------------------------------------------------------------
__global__ void ct_fold_weights(const float* __restrict__ w1,
                                const float* __restrict__ b1,
                                const float* __restrict__ w2,
                                float* __restrict__ ws) {
    int tid = threadIdx.x;
    if (tid < 576) {
        int tap = tid >> 6, cp = tid & 63;
        float acc = 0.f;
        #pragma unroll 8
        for (int c = 0; c < 64; ++c)
            acc += w2[(64 + c) * 9 + tap] * w1[(64 + c) * 64 + cp];
        ws[tid] = acc;
    } else if (tid < 585) {
        int tap = tid - 576;
        float acc = 0.f;
        for (int c = 0; c < 64; ++c)
            acc += w2[(64 + c) * 9 + tap] * b1[64 + c];
        ws[576 + tap] = acc;
    }
}

// ---------------------------------------------------------------------------
// Kernel 2 (PROVEN R3, 28us): partial Bk over a 16-channel slice.
// grid = 256*NPART blocks, 320 threads = 64 w * 5 t4 (float4 over t).
// Branch-free taps: OOB addresses clamped in-bounds, weight zeroed via
// vmask -> one straight 144-load / 576-FMA stream per thread (the empirical
// winner: every shorter/chopped stream variant measured ~2x slower).
// XCD swizzle: contiguous (part,b,h) chunk per XCD for h-halo L2 reuse.
// ---------------------------------------------------------------------------
template<int NPART>
__global__ __launch_bounds__(320) void ct_conv_bk(
        const float* __restrict__ x,
        const float* __restrict__ ws,
        float* __restrict__ bk) {
    __shared__ float weff[576];
    __shared__ float btap[9];
    int tid = threadIdx.x;
    for (int i = tid; i < 576; i += 320) weff[i] = ws[i];
    if (tid < 9) btap[tid] = ws[576 + tid];
    __syncthreads();

    constexpr int NCP = 64 / NPART;
    constexpr int CHUNK = 256 * NPART / 8;
    int g = (blockIdx.x & 7) * CHUNK + (blockIdx.x >> 3);
    int part = g >> 8;
    int nl = g & 255;
    int b = nl >> 6, h = nl & 63;
    int w = tid / 5, t4 = tid % 5;

    float vmask[9];
    int off[9];
    #pragma unroll
    for (int dh = 0; dh < 3; ++dh) {
        int hh = h + dh - 1;
        float hv = (hh >= 0 && hh < Hh) ? 1.f : 0.f;
        int hcl = hh < 0 ? 0 : (hh > Hh - 1 ? Hh - 1 : hh);
        #pragma unroll
        for (int dw = 0; dw < 3; ++dw) {
            int wc = w + dw - 1;
            float wvd = (wc >= 0 && wc < Ww) ? 1.f : 0.f;
            int wcl = wc < 0 ? 0 : (wc > Ww - 1 ? Ww - 1 : wc);
            vmask[dh * 3 + dw] = hv * wvd;
            off[dh * 3 + dw] = hcl * XH + wcl * XW;
        }
    }

    float bsum = 0.f;
    if (part == 0) {
        #pragma unroll
        for (int tap = 0; tap < 9; ++tap) bsum += btap[tap] * vmask[tap];
    }
    float4 acc = make_float4(bsum, bsum, bsum, bsum);

    const float* xb = x + b * XB + part * NCP * XC + t4 * 4;
    #pragma unroll 2
    for (int c = 0; c < NCP; ++c) {
        const float* xc = xb + c * XC;
        #pragma unroll
        for (int tap = 0; tap < 9; ++tap) {
            float wv = weff[tap * 64 + part * NCP + c] * vmask[tap];
            const float4 xv = *reinterpret_cast<const float4*>(xc + off[tap]);
            acc.x = fmaf(wv, xv.x, acc.x);
            acc.y = fmaf(wv, xv.y, acc.y);
            acc.z = fmaf(wv, xv.z, acc.z);
            acc.w = fmaf(wv, xv.w, acc.w);
        }
    }
    int site = nl * 64 + w;
    *reinterpret_cast<float4*>(bk + part * BKPLANE + site * 20 + t4 * 4) = acc;
}

// ---------------------------------------------------------------------------
// Kernel 3 (PROVEN R4, 22us): block = 8 consecutive sites, 256 threads,
// grid 2048 (8 blocks/CU x 4 waves). si = tid&7, cg = tid>>3; each thread
// owns channels c = cg*2+k. Bk partial-sum over 160 threads; softmax by 8
// threads; xbar -> R (LDS-transposed w1v, stride 65) -> broadcast store.
// ---------------------------------------------------------------------------
template<int NPART>
__global__ __launch_bounds__(256) void ct_attn_out(
        const float* __restrict__ x,
        const float* __restrict__ w1,
        const float* __restrict__ b1,
        const float* __restrict__ bk,
        float* __restrict__ out) {
    __shared__ float w1t[64 * 65];   // w1t[cp*65 + c] = w1v[c][cp]
    __shared__ float psm[8][20];
    __shared__ float xsh[8][65];
    int tid = threadIdx.x;
    #pragma unroll
    for (int k = 0; k < 16; ++k) {
        int j = tid + k * 256;            // coalesced global read
        int r = j >> 6, q = j & 63;
        w1t[q * 65 + r] = w1[8192 + j];   // w1v row r, col q
    }

    int site0 = blockIdx.x * 8;

    if (tid < 160) {
        int si = tid / 20, i = tid % 20;
        float v = 0.f;
        #pragma unroll
        for (int pt = 0; pt < NPART; ++pt)
            v += bk[pt * BKPLANE + (site0 + si) * 20 + i];
        psm[si][i] = v;
    }
    __syncthreads();

    if (tid < 8) {
        float p[20];
        #pragma unroll
        for (int i = 0; i < 20; ++i) p[i] = psm[tid][i];
        float m = p[0];
        #pragma unroll
        for (int i = 1; i < 20; ++i) m = fmaxf(m, p[i]);
        float ssum = 0.f;
        #pragma unroll
        for (int i = 0; i < 20; ++i) { p[i] = __expf(p[i] - m); ssum += p[i]; }
        float inv = 1.f / ssum;
        #pragma unroll
        for (int i = 0; i < 20; ++i) psm[tid][i] = p[i] * inv;
    }
    __syncthreads();

    int si = tid & 7, cg = tid >> 3;
    int site = site0 + si;
    int b = site >> 12, hw = site & 4095;

    #pragma unroll
    for (int k = 0; k < 2; ++k) {
        int c = cg * 2 + k;
        const float* xp = x + (b * 64 + c) * XC + hw * 20;
        float xbv = 0.f;
        #pragma unroll
        for (int i = 0; i < 5; ++i) {
            float4 xv = reinterpret_cast<const float4*>(xp)[i];
            xbv = fmaf(psm[si][4 * i],     xv.x, xbv);
            xbv = fmaf(psm[si][4 * i + 1], xv.y, xbv);
            xbv = fmaf(psm[si][4 * i + 2], xv.z, xbv);
            xbv = fmaf(psm[si][4 * i + 3], xv.w, xbv);
        }
        xsh[si][c] = xbv;
    }
    __syncthreads();

    #pragma unroll
    for (int k = 0; k < 2; ++k) {
        int c = cg * 2 + k;
        float R = b1[128 + c];
        #pragma unroll 8
        for (int cp = 0; cp < 64; ++cp)
            R = fmaf(w1t[cp * 65 + c], xsh[si][cp], R);
        float* op = out + (b * 64 + c) * XC + hw * 20;
        float4 rv = make_float4(R, R, R, R);
        #pragma unroll
        for (int s4 = 0; s4 < 5; ++s4)
            reinterpret_cast<float4*>(op)[s4] = rv;
    }
}

extern "C" void kernel_launch(void* const* d_in, const int* in_sizes, int n_in,
                              void* d_out, int out_size, void* d_ws, size_t ws_size,
                              hipStream_t stream) {
    const float* x  = (const float*)d_in[0];
    const float* w1 = (const float*)d_in[1];
    const float* b1 = (const float*)d_in[2];
    const float* w2 = (const float*)d_in[3];
    // d_in[4] (b2) is mathematically dead: it cancels in the softmax over t.
    float* ws    = (float*)d_ws;
    float* bkbuf = ws + 640;
    float* out   = (float*)d_out;

    ct_fold_weights<<<1, 640, 0, stream>>>(w1, b1, w2, ws);

    size_t need4 = (size_t)(640 + 4 * BKPLANE) * sizeof(float);
    if (ws_size >= need4) {
        ct_conv_bk<4><<<1024, 320, 0, stream>>>(x, ws, bkbuf);
        ct_attn_out<4><<<2048, 256, 0, stream>>>(x, w1, b1, bkbuf, out);
    } else {
        ct_conv_bk<1><<<256, 320, 0, stream>>>(x, ws, bkbuf);
        ct_attn_out<1><<<2048, 256, 0, stream>>>(x, w1, b1, bkbuf, out);
    }
}

// Round 11
// 74.275 us; speedup vs baseline: 1.1326x; 1.0056x over previous
//
#include <hip/hip_runtime.h>
#include <math.h>

// Problem constants
#define Bb 4
#define Cc 64
#define Hh 64
#define Ww 64
#define Ss 20

constexpr int XC = Hh * Ww * Ss;   // 81920  : x channel stride (floats)
constexpr int XH = Ww * Ss;        // 1280   : x row stride
constexpr int XW = Ss;             // 20     : x col stride
constexpr int XB = Cc * XC;        // 5242880: x batch stride
constexpr int NSITE = Bb * Hh * Ww;    // 16384
constexpr int PSMF  = NSITE * Ss;      // 327680 floats: softmax'd scores

// ws layout (floats): [0,576) Weff[tap][c'], [576,585) btap[tap],
//                     [640, 640+PSMF) psm  (softmax'd attention weights)

// ---------------------------------------------------------------------------
// Kernel 1: fold the K-branch 1x1 conv into the 3x3 conv.
// Weff[tap][c'] = sum_c w2[0,64+c,tap] * w1[64+c, c']
// btap[tap]     = sum_c w2[0,64+c,tap] * b1[64+c]
// ---------------------------------------------------------------------------
__global__ void ct_fold_weights(const float* __restrict__ w1,
                                const float* __restrict__ b1,
                                const float* __restrict__ w2,
                                float* __restrict__ ws) {
    int tid = threadIdx.x;
    if (tid < 576) {
        int tap = tid >> 6, cp = tid & 63;
        float acc = 0.f;
        #pragma unroll 8
        for (int c = 0; c < 64; ++c)
            acc += w2[(64 + c) * 9 + tap] * w1[(64 + c) * 64 + cp];
        ws[tid] = acc;
    } else if (tid < 585) {
        int tap = tid - 576;
        float acc = 0.f;
        for (int c = 0; c < 64; ++c)
            acc += w2[(64 + c) * 9 + tap] * b1[64 + c];
        ws[576 + tap] = acc;
    }
}

// ---------------------------------------------------------------------------
// Kernel 2: conv + softmax fused, PROVEN conv micro-structure preserved.
// Block = (b, h, w-half): 32 sites. 640 threads = cg(4) x w16(32) x t4(5).
// Each thread: the R3-proven 144-load/576-FMA clamped-gather stream over its
// 16 channels (no barriers/stores inside the loop). grid 512 -> 2 blocks/CU
// -> 20 waves/CU (same residency as the proven conv4 config).
// Channel-group partials meet in LDS: 640-thread reduce + bias, 32-thread
// softmax, coalesced psm write (1.3 MB replaces the 5.2 MB bk round-trip).
// XCD swizzle: XCD owns contiguous (b, h) range -> h-halo L2 reuse.
// ---------------------------------------------------------------------------
__global__ __launch_bounds__(640) void ct_conv_sm(
        const float* __restrict__ x,
        const float* __restrict__ ws,
        float* __restrict__ psm) {
    __shared__ float weff[576];
    __shared__ float btL[9];
    __shared__ float bkp[4][32][20];
    __shared__ float psmL[32][20];
    int tid = threadIdx.x;

    for (int i = tid; i < 576; i += 640) weff[i] = ws[i];
    if (tid < 9) btL[tid] = ws[576 + tid];

    // g = b*128 + h*2 + wh ; XCD owns 64 consecutive g = one b, 32 h rows
    int g = (blockIdx.x & 7) * 64 + (blockIdx.x >> 3);
    int wh = g & 1;
    int h  = (g >> 1) & 63;
    int b  = g >> 7;

    int cg = tid / 160, r = tid % 160;
    int w16 = r / 5, t4 = r % 5;
    int w = wh * 32 + w16;

    float vmask[9];
    int off[9];
    #pragma unroll
    for (int dh = 0; dh < 3; ++dh) {
        int hh = h + dh - 1;
        float hv = (hh >= 0 && hh < Hh) ? 1.f : 0.f;
        int hcl = hh < 0 ? 0 : (hh > Hh - 1 ? Hh - 1 : hh);
        #pragma unroll
        for (int dw = 0; dw < 3; ++dw) {
            int wc = w + dw - 1;
            float wvd = (wc >= 0 && wc < Ww) ? 1.f : 0.f;
            int wcl = wc < 0 ? 0 : (wc > Ww - 1 ? Ww - 1 : wc);
            vmask[dh * 3 + dw] = hv * wvd;
            off[dh * 3 + dw] = hcl * XH + wcl * XW;
        }
    }
    __syncthreads();   // weff ready

    float4 acc = make_float4(0.f, 0.f, 0.f, 0.f);
    const float* xb = x + b * XB + cg * 16 * XC + t4 * 4;
    #pragma unroll 2
    for (int c = 0; c < 16; ++c) {
        const float* xc = xb + c * XC;
        #pragma unroll
        for (int tap = 0; tap < 9; ++tap) {
            float wv = weff[tap * 64 + cg * 16 + c] * vmask[tap];
            const float4 xv = *reinterpret_cast<const float4*>(xc + off[tap]);
            acc.x = fmaf(wv, xv.x, acc.x);
            acc.y = fmaf(wv, xv.y, acc.y);
            acc.z = fmaf(wv, xv.z, acc.z);
            acc.w = fmaf(wv, xv.w, acc.w);
        }
    }
    *reinterpret_cast<float4*>(&bkp[cg][w16][t4 * 4]) = acc;
    __syncthreads();

    // reduce 4 channel-group partials + per-site valid-tap bias
    {
        int sw = tid / 20, t = tid % 20;      // 640 = 32*20 exactly
        float v = bkp[0][sw][t] + bkp[1][sw][t] + bkp[2][sw][t] + bkp[3][sw][t];
        int wsit = wh * 32 + sw;
        float bs = 0.f;
        #pragma unroll
        for (int dh = 0; dh < 3; ++dh) {
            int hh = h + dh - 1;
            if (hh < 0 || hh >= Hh) continue;
            #pragma unroll
            for (int dw = 0; dw < 3; ++dw) {
                int wc = wsit + dw - 1;
                if (wc < 0 || wc >= Ww) continue;
                bs += btL[dh * 3 + dw];
            }
        }
        psmL[sw][t] = v + bs;
    }
    __syncthreads();

    if (tid < 32) {                           // softmax per site
        float p[20];
        #pragma unroll
        for (int i = 0; i < 20; ++i) p[i] = psmL[tid][i];
        float m = p[0];
        #pragma unroll
        for (int i = 1; i < 20; ++i) m = fmaxf(m, p[i]);
        float ssum = 0.f;
        #pragma unroll
        for (int i = 0; i < 20; ++i) { p[i] = __expf(p[i] - m); ssum += p[i]; }
        float inv = 1.f / ssum;
        #pragma unroll
        for (int i = 0; i < 20; ++i) psmL[tid][i] = p[i] * inv;
    }
    __syncthreads();

    {
        int sw = tid / 20, t = tid % 20;
        int site = b * 4096 + h * 64 + wh * 32 + sw;
        psm[site * 20 + t] = psmL[sw][t];     // coalesced 2560 B per block
    }
}

// ---------------------------------------------------------------------------
// Kernel 3 (attn-lite): proven R4 8-site kernel, softmax already done.
// block = 8 sites, 256 threads, grid 2048. Load psm (160 thr, 1 barrier),
// xbar -> R (LDS-transposed w1v, stride 65) -> broadcast store.
// ---------------------------------------------------------------------------
__global__ __launch_bounds__(256) void ct_attn_lite(
        const float* __restrict__ x,
        const float* __restrict__ w1,
        const float* __restrict__ b1,
        const float* __restrict__ psm,
        float* __restrict__ out) {
    __shared__ float w1t[64 * 65];   // w1t[cp*65 + c] = w1v[c][cp]
    __shared__ float psmL[8][20];
    __shared__ float xsh[8][65];
    int tid = threadIdx.x;
    #pragma unroll
    for (int k = 0; k < 16; ++k) {
        int j = tid + k * 256;            // coalesced global read
        int r = j >> 6, q = j & 63;
        w1t[q * 65 + r] = w1[8192 + j];   // w1v row r, col q
    }

    int site0 = blockIdx.x * 8;
    if (tid < 160) {
        int si = tid / 20, i = tid % 20;
        psmL[si][i] = psm[(site0 + si) * 20 + i];
    }
    __syncthreads();

    int si = tid & 7, cg = tid >> 3;
    int site = site0 + si;
    int b = site >> 12, hw = site & 4095;

    #pragma unroll
    for (int k = 0; k < 2; ++k) {
        int c = cg * 2 + k;
        const float* xp = x + (b * 64 + c) * XC + hw * 20;
        float xbv = 0.f;
        #pragma unroll
        for (int i = 0; i < 5; ++i) {
            float4 xv = reinterpret_cast<const float4*>(xp)[i];
            xbv = fmaf(psmL[si][4 * i],     xv.x, xbv);
            xbv = fmaf(psmL[si][4 * i + 1], xv.y, xbv);
            xbv = fmaf(psmL[si][4 * i + 2], xv.z, xbv);
            xbv = fmaf(psmL[si][4 * i + 3], xv.w, xbv);
        }
        xsh[si][c] = xbv;
    }
    __syncthreads();

    #pragma unroll
    for (int k = 0; k < 2; ++k) {
        int c = cg * 2 + k;
        float R = b1[128 + c];
        #pragma unroll 8
        for (int cp = 0; cp < 64; ++cp)
            R = fmaf(w1t[cp * 65 + c], xsh[si][cp], R);
        float* op = out + (b * 64 + c) * XC + hw * 20;
        float4 rv = make_float4(R, R, R, R);
        #pragma unroll
        for (int s4 = 0; s4 < 5; ++s4)
            reinterpret_cast<float4*>(op)[s4] = rv;
    }
}

extern "C" void kernel_launch(void* const* d_in, const int* in_sizes, int n_in,
                              void* d_out, int out_size, void* d_ws, size_t ws_size,
                              hipStream_t stream) {
    const float* x  = (const float*)d_in[0];
    const float* w1 = (const float*)d_in[1];
    const float* b1 = (const float*)d_in[2];
    const float* w2 = (const float*)d_in[3];
    // d_in[4] (b2) is mathematically dead: it cancels in the softmax over t.
    float* ws  = (float*)d_ws;
    float* psm = ws + 640;
    float* out = (float*)d_out;

    ct_fold_weights<<<1, 640, 0, stream>>>(w1, b1, w2, ws);
    ct_conv_sm<<<512, 640, 0, stream>>>(x, ws, psm);
    ct_attn_lite<<<2048, 256, 0, stream>>>(x, w1, b1, psm, out);
}